// Round 14
// baseline (95.727 us; speedup 1.0000x reference)
//
#include <hip/hip_runtime.h>

#define NN    8192
#define INF_  256
#define OUTF  64
#define NH    2
#define NE    262144
#define NW    256        // 32-bit words per bitmap row
#define SLOPE 0.2f

typedef __attribute__((ext_vector_type(8))) short short8;
typedef __attribute__((ext_vector_type(4))) float f32x4;
typedef __attribute__((ext_vector_type(2))) long long ll2;

__device__ __forceinline__ unsigned short f2bf(float f) {
  unsigned int u = __float_as_uint(f);
  u += 0x7fffu + ((u >> 16) & 1u);   // round-to-nearest-even
  return (unsigned short)(u >> 16);
}
__device__ __forceinline__ float bf2f(unsigned short u) {
  return __uint_as_float(((unsigned int)u) << 16);
}

// GEMM xh = x@W (512 blocks, 16 rows each), bf16 MFMA, xh stored BF16,
// s1/s2 epilogue from f32 accumulator (interleaved float2).
__global__ __launch_bounds__(256) void gemm_kernel(
    const float* __restrict__ x, const float* __restrict__ W,
    const float* __restrict__ a1, const float* __restrict__ a2,
    unsigned short* __restrict__ xhb, float2* __restrict__ s1v,
    float2* __restrict__ s2v) {
  const int b = blockIdx.x, t = threadIdx.x;
  const int l = t & 63, w = t >> 6;
  const int lo = l & 15, hi = l >> 4;
  const int n0 = b * 16;
  __shared__ float p1s[4][16], p2s[4][16];

  const int tc0 = w * 2, tc1 = w * 2 + 1;
  const int h0 = tc0 >> 2, h1 = tc1 >> 2;
  const int col0 = (tc0 * 16 + lo) & 63, col1 = (tc1 * 16 + lo) & 63;
  const float* wp0 = W + (size_t)h0 * (INF_ * OUTF) + (size_t)(hi * 8) * OUTF + col0;
  const float* wp1 = W + (size_t)h1 * (INF_ * OUTF) + (size_t)(hi * 8) * OUTF + col1;
  const float* xp = x + (size_t)(n0 + lo) * INF_ + hi * 8;

  f32x4 acc0 = {0.f, 0.f, 0.f, 0.f};
  f32x4 acc1 = {0.f, 0.f, 0.f, 0.f};

#define KSTEP(ks)                                                              \
  {                                                                            \
    const float4 f0 = *(const float4*)(xp + (ks) * 32);                        \
    const float4 f1 = *(const float4*)(xp + (ks) * 32 + 4);                    \
    short8 a_;                                                                 \
    a_[0] = (short)f2bf(f0.x); a_[1] = (short)f2bf(f0.y);                      \
    a_[2] = (short)f2bf(f0.z); a_[3] = (short)f2bf(f0.w);                      \
    a_[4] = (short)f2bf(f1.x); a_[5] = (short)f2bf(f1.y);                      \
    a_[6] = (short)f2bf(f1.z); a_[7] = (short)f2bf(f1.w);                      \
    const float* wq0 = wp0 + (size_t)(ks) * 32 * OUTF;                         \
    short8 b0_;                                                                \
    b0_[0] = (short)f2bf(wq0[0 * OUTF]); b0_[1] = (short)f2bf(wq0[1 * OUTF]);  \
    b0_[2] = (short)f2bf(wq0[2 * OUTF]); b0_[3] = (short)f2bf(wq0[3 * OUTF]);  \
    b0_[4] = (short)f2bf(wq0[4 * OUTF]); b0_[5] = (short)f2bf(wq0[5 * OUTF]);  \
    b0_[6] = (short)f2bf(wq0[6 * OUTF]); b0_[7] = (short)f2bf(wq0[7 * OUTF]);  \
    acc0 = __builtin_amdgcn_mfma_f32_16x16x32_bf16(a_, b0_, acc0, 0, 0, 0);    \
    const float* wq1 = wp1 + (size_t)(ks) * 32 * OUTF;                         \
    short8 b1_;                                                                \
    b1_[0] = (short)f2bf(wq1[0 * OUTF]); b1_[1] = (short)f2bf(wq1[1 * OUTF]);  \
    b1_[2] = (short)f2bf(wq1[2 * OUTF]); b1_[3] = (short)f2bf(wq1[3 * OUTF]);  \
    b1_[4] = (short)f2bf(wq1[4 * OUTF]); b1_[5] = (short)f2bf(wq1[5 * OUTF]);  \
    b1_[6] = (short)f2bf(wq1[6 * OUTF]); b1_[7] = (short)f2bf(wq1[7 * OUTF]);  \
    acc1 = __builtin_amdgcn_mfma_f32_16x16x32_bf16(a_, b1_, acc1, 0, 0, 0);    \
  }

  KSTEP(0) KSTEP(1) KSTEP(2) KSTEP(3) KSTEP(4) KSTEP(5) KSTEP(6) KSTEP(7)
#undef KSTEP

  {
    unsigned short* o0 = xhb + ((size_t)h0 * NN + n0 + hi * 4) * OUTF + col0;
    unsigned short* o1 = xhb + ((size_t)h1 * NN + n0 + hi * 4) * OUTF + col1;
    o0[0 * OUTF] = f2bf(acc0[0]); o0[1 * OUTF] = f2bf(acc0[1]);
    o0[2 * OUTF] = f2bf(acc0[2]); o0[3 * OUTF] = f2bf(acc0[3]);
    o1[0 * OUTF] = f2bf(acc1[0]); o1[1 * OUTF] = f2bf(acc1[1]);
    o1[2 * OUTF] = f2bf(acc1[2]); o1[3 * OUTF] = f2bf(acc1[3]);
  }
  const float a10 = a1[h0 * OUTF + col0], a11 = a1[h1 * OUTF + col1];
  const float a20 = a2[h0 * OUTF + col0], a21 = a2[h1 * OUTF + col1];
#pragma unroll
  for (int r = 0; r < 4; ++r) {
    float p1v = acc0[r] * a10 + acc1[r] * a11;
    float p2v = acc0[r] * a20 + acc1[r] * a21;
#pragma unroll
    for (int s = 1; s < 16; s <<= 1) {
      p1v += __shfl_xor(p1v, s, 64);
      p2v += __shfl_xor(p2v, s, 64);
    }
    if (lo == 0) {
      p1s[w][hi * 4 + r] = p1v;
      p2s[w][hi * 4 + r] = p2v;
    }
  }
  __syncthreads();
  if (t < 16) {
    float2 v1, v2;
    v1.x = p1s[0][t] + p1s[1][t];  v1.y = p1s[2][t] + p1s[3][t];
    v2.x = p2s[0][t] + p2s[1][t];  v2.y = p2s[2][t] + p2s[3][t];
    s1v[n0 + t] = v1;
    s2v[n0 + t] = v2;
  }
}

// Edge scatter: bitmap atomicOr, fire-and-forget, idempotent (replay-safe).
__global__ __launch_bounds__(256) void edge_kernel(const int* __restrict__ ei,
                                                   unsigned* __restrict__ bits) {
  const int b = blockIdx.x, t = threadIdx.x;
  const int e0 = b * 512 + t * 2;
  __shared__ int s_nz;
  if (t == 0) s_nz = 0;
  __syncthreads();
  if (((const unsigned int*)ei)[2 * e0 + 1] != 0u ||
      ((const unsigned int*)ei)[2 * e0 + 3] != 0u)
    s_nz = 1;
  __syncthreads();
  int i0, j0, i1, j1;
  if (s_nz == 0) {  // int64
    const ll2 a = *(const ll2*)((const long long*)ei + e0);
    const ll2 c = *(const ll2*)((const long long*)ei + NE + e0);
    i0 = (int)a[0]; i1 = (int)a[1]; j0 = (int)c[0]; j1 = (int)c[1];
  } else {
    const int2 a = *(const int2*)(ei + e0);
    const int2 c = *(const int2*)(ei + NE + e0);
    i0 = a.x; i1 = a.y; j0 = c.x; j1 = c.y;
  }
  atomicOr(&bits[(size_t)i0 * NW + (j0 >> 5)], 1u << (j0 & 31));
  atomicOr(&bits[(size_t)i1 * NW + (j1 >> 5)], 1u << (j1 & 31));
}

// agg: block per node (128 thr = 2 waves, wave = head). Bitmap extraction
// (popcount + prefix + ffs), register softmax, BF16 gathers (8 rows per
// dwordx4: row-slot r8 = lane>>3, chunk c8 = lane&7).
__global__ __launch_bounds__(128) void agg_kernel(const unsigned short* __restrict__ xhb,
                                                  const float2* __restrict__ s1v,
                                                  const float2* __restrict__ s2v,
                                                  const unsigned* __restrict__ bits,
                                                  float* __restrict__ out) {
  const int i = blockIdx.x;
  const int t = threadIdx.x;
  const int h = t >> 6, lane = t & 63;
  __shared__ int   cjs[NH][256];
  __shared__ float wts[NH][256];

  const uint4 bv = *(const uint4*)(bits + (size_t)i * NW + lane * 4);
  const int myc = __popc(bv.x) + __popc(bv.y) + __popc(bv.z) + __popc(bv.w);
  int incl = myc;
#pragma unroll
  for (int s = 1; s < 64; s <<= 1) {
    const int v = __shfl_up(incl, s, 64);
    if (lane >= s) incl += v;
  }
  int pos = incl - myc;
  const int dt = __shfl(incl, 63, 64);
  const int d = __builtin_amdgcn_readfirstlane(dt > 256 ? 256 : dt);
  {
    unsigned wv; int bj;
    wv = bv.x; bj = lane * 128;
    while (wv) { const int bb = __ffs(wv) - 1; if (pos < 256) cjs[h][pos] = bj + bb; ++pos; wv &= wv - 1; }
    wv = bv.y; bj = lane * 128 + 32;
    while (wv) { const int bb = __ffs(wv) - 1; if (pos < 256) cjs[h][pos] = bj + bb; ++pos; wv &= wv - 1; }
    wv = bv.z; bj = lane * 128 + 64;
    while (wv) { const int bb = __ffs(wv) - 1; if (pos < 256) cjs[h][pos] = bj + bb; ++pos; wv &= wv - 1; }
    wv = bv.w; bj = lane * 128 + 96;
    while (wv) { const int bb = __ffs(wv) - 1; if (pos < 256) cjs[h][pos] = bj + bb; ++pos; wv &= wv - 1; }
  }
  __syncthreads();

  const unsigned short* base = xhb + (size_t)h * NN * OUTF;
  const int r8 = lane >> 3, c8 = lane & 7;
  float accv[8] = {0.f, 0.f, 0.f, 0.f, 0.f, 0.f, 0.f, 0.f};
  float inv;

  if (d == 0) {   // uniform softmax over ALL nodes (never hit at this density)
    for (int p = r8; p < NN; p += 8) {
      const short8 v = *(const short8*)(base + (size_t)p * OUTF + c8 * 8);
#pragma unroll
      for (int m = 0; m < 8; ++m) accv[m] += bf2f((unsigned short)v[m]);
    }
    inv = 1.f / (float)NN;
  } else if (d <= 64) {
    const bool kp = lane < d;
    const int j = kp ? cjs[h][lane] : 0;
    float sc = -1e30f;
    if (kp) {
      const float2 s1i2 = s1v[i];
      const float2 s2j2 = s2v[j];
      sc = (h ? s1i2.y : s1i2.x) + (h ? s2j2.y : s2j2.x);
      sc = (sc >= 0.f) ? sc : SLOPE * sc;
    }
    float m = sc;
#pragma unroll
    for (int s = 32; s > 0; s >>= 1) m = fmaxf(m, __shfl_xor(m, s, 64));
    const float wt = kp ? __expf(sc - m) : 0.f;
    float ds = wt;
#pragma unroll
    for (int s = 32; s > 0; s >>= 1) ds += __shfl_xor(ds, s, 64);
    inv = 1.f / ds;
#pragma unroll 2
    for (int p = 0; p < d; p += 8) {
      const int pr = p + r8;
      float ww = __shfl(wt, pr, 64);
      int   jj = __shfl(j,  pr, 64);
      ww = (pr < d) ? ww : 0.f;
      jj = (ww > 0.f) ? jj : 0;
      const short8 v = *(const short8*)(base + (size_t)jj * OUTF + c8 * 8);
#pragma unroll
      for (int m2 = 0; m2 < 8; ++m2) accv[m2] += ww * bf2f((unsigned short)v[m2]);
    }
  } else {
    // slow path: 64 < d <= 256 (list already unique)
    const float2 s1i2 = s1v[i];
    const float s1i = h ? s1i2.y : s1i2.x;
    float m = -1e30f;
    for (int p = lane; p < d; p += 64) {
      const float2 s2j2 = s2v[cjs[h][p]];
      float sc = s1i + (h ? s2j2.y : s2j2.x);
      sc = (sc >= 0.f) ? sc : SLOPE * sc;
      wts[h][p] = sc;
      m = fmaxf(m, sc);
    }
#pragma unroll
    for (int s = 32; s > 0; s >>= 1) m = fmaxf(m, __shfl_xor(m, s, 64));
    float ds = 0.f;
    for (int p = lane; p < d; p += 64) {
      const float w2 = __expf(wts[h][p] - m);
      wts[h][p] = w2;
      ds += w2;
    }
#pragma unroll
    for (int s = 32; s > 0; s >>= 1) ds += __shfl_xor(ds, s, 64);
    inv = 1.f / ds;
#pragma unroll 2
    for (int p = 0; p < d; p += 8) {
      const int pr = p + r8;
      const bool ok = pr < d;
      const float ww = ok ? wts[h][pr] : 0.f;
      const int   jj = ok ? cjs[h][pr] : 0;
      const short8 v = *(const short8*)(base + (size_t)jj * OUTF + c8 * 8);
#pragma unroll
      for (int m2 = 0; m2 < 8; ++m2) accv[m2] += ww * bf2f((unsigned short)v[m2]);
    }
  }

#pragma unroll
  for (int m2 = 0; m2 < 8; ++m2) {
    accv[m2] += __shfl_xor(accv[m2], 8, 64);
    accv[m2] += __shfl_xor(accv[m2], 16, 64);
    accv[m2] += __shfl_xor(accv[m2], 32, 64);
  }
  if (lane < 8) {
    float4 o0, o1;
    o0.x = accv[0] * inv; o0.y = accv[1] * inv;
    o0.z = accv[2] * inv; o0.w = accv[3] * inv;
    o1.x = accv[4] * inv; o1.y = accv[5] * inv;
    o1.z = accv[6] * inv; o1.w = accv[7] * inv;
    float* op = out + (size_t)i * (NH * OUTF) + h * OUTF + lane * 8;
    *(float4*)op = o0;
    *(float4*)(op + 4) = o1;
  }
}

extern "C" void kernel_launch(void* const* d_in, const int* in_sizes, int n_in,
                              void* d_out, int out_size, void* d_ws, size_t ws_size,
                              hipStream_t stream) {
  const float* x  = (const float*)d_in[0];
  const int*   ei = (const int*)d_in[1];
  const float* W  = (const float*)d_in[2];
  const float* a1 = (const float*)d_in[3];
  const float* a2 = (const float*)d_in[4];
  float* out = (float*)d_out;

  char* ws = (char*)d_ws;
  unsigned*       bits = (unsigned*)(ws);                            // 8 MB
  unsigned short* xhb  = (unsigned short*)(ws + (8u << 20));         // 2 MB
  float2*         s1v  = (float2*)(ws + (10u << 20));                // 64 KB
  float2*         s2v  = (float2*)(ws + (10u << 20) + (64u << 10));  // 64 KB

  hipMemsetAsync(bits, 0, (size_t)NN * NW * 4, stream);
  gemm_kernel<<<512, 256, 0, stream>>>(x, W, a1, a2, xhb, s1v, s2v);
  // ABLATION: edge kernel 5x (atomicOr idempotent). dur = base + 4*(edge+gap).
  edge_kernel<<<512, 256, 0, stream>>>(ei, bits);
  edge_kernel<<<512, 256, 0, stream>>>(ei, bits);
  edge_kernel<<<512, 256, 0, stream>>>(ei, bits);
  edge_kernel<<<512, 256, 0, stream>>>(ei, bits);
  edge_kernel<<<512, 256, 0, stream>>>(ei, bits);
  agg_kernel<<<NN, 128, 0, stream>>>(xhb, s1v, s2v, bits, out);
}

// Round 15
// 43.784 us; speedup vs baseline: 2.1863x; 2.1863x over previous
//
#include <hip/hip_runtime.h>

#define NN    8192
#define INF_  256
#define OUTF  64
#define NH    2
#define NE    262144
#define NW    256        // 32-bit words per bitmap row
#define SLOPE 0.2f

typedef __attribute__((ext_vector_type(8))) short short8;
typedef __attribute__((ext_vector_type(4))) float f32x4;

__device__ __forceinline__ unsigned short f2bf(float f) {
  unsigned int u = __float_as_uint(f);
  u += 0x7fffu + ((u >> 16) & 1u);   // round-to-nearest-even
  return (unsigned short)(u >> 16);
}
__device__ __forceinline__ float bf2f(unsigned short u) {
  return __uint_as_float(((unsigned int)u) << 16);
}

// GEMM xh = x@W (512 blocks, 16 rows each), bf16 MFMA, xh stored BF16,
// s1/s2 epilogue. Each block ALSO zeroes its 16KB slice of the edge bitmap
// (replaces the memset dispatch; stream order gemm->edge makes this safe).
__global__ __launch_bounds__(256) void gemm_kernel(
    const float* __restrict__ x, const float* __restrict__ W,
    const float* __restrict__ a1, const float* __restrict__ a2,
    unsigned short* __restrict__ xhb, float2* __restrict__ s1v,
    float2* __restrict__ s2v, unsigned* __restrict__ bits) {
  const int b = blockIdx.x, t = threadIdx.x;

  // zero this block's bitmap slice: 4096 words = 256 thr x 4 uint4
  {
    uint4* bp = (uint4*)(bits + (size_t)b * 4096) + t;
    const uint4 z = {0u, 0u, 0u, 0u};
    bp[0] = z; bp[256] = z; bp[512] = z; bp[768] = z;
  }

  const int l = t & 63, w = t >> 6;
  const int lo = l & 15, hi = l >> 4;
  const int n0 = b * 16;
  __shared__ float p1s[4][16], p2s[4][16];

  const int tc0 = w * 2, tc1 = w * 2 + 1;
  const int h0 = tc0 >> 2, h1 = tc1 >> 2;
  const int col0 = (tc0 * 16 + lo) & 63, col1 = (tc1 * 16 + lo) & 63;
  const float* wp0 = W + (size_t)h0 * (INF_ * OUTF) + (size_t)(hi * 8) * OUTF + col0;
  const float* wp1 = W + (size_t)h1 * (INF_ * OUTF) + (size_t)(hi * 8) * OUTF + col1;
  const float* xp = x + (size_t)(n0 + lo) * INF_ + hi * 8;

  f32x4 acc0 = {0.f, 0.f, 0.f, 0.f};
  f32x4 acc1 = {0.f, 0.f, 0.f, 0.f};

#define KSTEP(ks)                                                              \
  {                                                                            \
    const float4 f0 = *(const float4*)(xp + (ks) * 32);                        \
    const float4 f1 = *(const float4*)(xp + (ks) * 32 + 4);                    \
    short8 a_;                                                                 \
    a_[0] = (short)f2bf(f0.x); a_[1] = (short)f2bf(f0.y);                      \
    a_[2] = (short)f2bf(f0.z); a_[3] = (short)f2bf(f0.w);                      \
    a_[4] = (short)f2bf(f1.x); a_[5] = (short)f2bf(f1.y);                      \
    a_[6] = (short)f2bf(f1.z); a_[7] = (short)f2bf(f1.w);                      \
    const float* wq0 = wp0 + (size_t)(ks) * 32 * OUTF;                         \
    short8 b0_;                                                                \
    b0_[0] = (short)f2bf(wq0[0 * OUTF]); b0_[1] = (short)f2bf(wq0[1 * OUTF]);  \
    b0_[2] = (short)f2bf(wq0[2 * OUTF]); b0_[3] = (short)f2bf(wq0[3 * OUTF]);  \
    b0_[4] = (short)f2bf(wq0[4 * OUTF]); b0_[5] = (short)f2bf(wq0[5 * OUTF]);  \
    b0_[6] = (short)f2bf(wq0[6 * OUTF]); b0_[7] = (short)f2bf(wq0[7 * OUTF]);  \
    acc0 = __builtin_amdgcn_mfma_f32_16x16x32_bf16(a_, b0_, acc0, 0, 0, 0);    \
    const float* wq1 = wp1 + (size_t)(ks) * 32 * OUTF;                         \
    short8 b1_;                                                                \
    b1_[0] = (short)f2bf(wq1[0 * OUTF]); b1_[1] = (short)f2bf(wq1[1 * OUTF]);  \
    b1_[2] = (short)f2bf(wq1[2 * OUTF]); b1_[3] = (short)f2bf(wq1[3 * OUTF]);  \
    b1_[4] = (short)f2bf(wq1[4 * OUTF]); b1_[5] = (short)f2bf(wq1[5 * OUTF]);  \
    b1_[6] = (short)f2bf(wq1[6 * OUTF]); b1_[7] = (short)f2bf(wq1[7 * OUTF]);  \
    acc1 = __builtin_amdgcn_mfma_f32_16x16x32_bf16(a_, b1_, acc1, 0, 0, 0);    \
  }

  KSTEP(0) KSTEP(1) KSTEP(2) KSTEP(3) KSTEP(4) KSTEP(5) KSTEP(6) KSTEP(7)
#undef KSTEP

  {
    unsigned short* o0 = xhb + ((size_t)h0 * NN + n0 + hi * 4) * OUTF + col0;
    unsigned short* o1 = xhb + ((size_t)h1 * NN + n0 + hi * 4) * OUTF + col1;
    o0[0 * OUTF] = f2bf(acc0[0]); o0[1 * OUTF] = f2bf(acc0[1]);
    o0[2 * OUTF] = f2bf(acc0[2]); o0[3 * OUTF] = f2bf(acc0[3]);
    o1[0 * OUTF] = f2bf(acc1[0]); o1[1 * OUTF] = f2bf(acc1[1]);
    o1[2 * OUTF] = f2bf(acc1[2]); o1[3 * OUTF] = f2bf(acc1[3]);
  }
  const float a10 = a1[h0 * OUTF + col0], a11 = a1[h1 * OUTF + col1];
  const float a20 = a2[h0 * OUTF + col0], a21 = a2[h1 * OUTF + col1];
#pragma unroll
  for (int r = 0; r < 4; ++r) {
    float p1v = acc0[r] * a10 + acc1[r] * a11;
    float p2v = acc0[r] * a20 + acc1[r] * a21;
#pragma unroll
    for (int s = 1; s < 16; s <<= 1) {
      p1v += __shfl_xor(p1v, s, 64);
      p2v += __shfl_xor(p2v, s, 64);
    }
    if (lo == 0) {
      p1s[w][hi * 4 + r] = p1v;
      p2s[w][hi * 4 + r] = p2v;
    }
  }
  __syncthreads();
  if (t < 16) {
    float2 v1, v2;
    v1.x = p1s[0][t] + p1s[1][t];  v1.y = p1s[2][t] + p1s[3][t];
    v2.x = p2s[0][t] + p2s[1][t];  v2.y = p2s[2][t] + p2s[3][t];
    s1v[n0 + t] = v1;
    s2v[n0 + t] = v2;
  }
}

// Edge scatter: bitmap atomicOr, fire-and-forget, idempotent. 1 edge/thread,
// 1024 blocks (max wave-level atomic parallelism).
__global__ __launch_bounds__(256) void edge_kernel(const int* __restrict__ ei,
                                                   unsigned* __restrict__ bits) {
  const int e = blockIdx.x * 256 + threadIdx.x;
  __shared__ int s_nz;
  if (threadIdx.x == 0) s_nz = 0;
  __syncthreads();
  if (((const unsigned int*)ei)[2 * e + 1] != 0u) s_nz = 1;
  __syncthreads();
  int i, j;
  if (s_nz == 0) {  // int64
    i = (int)((const long long*)ei)[e];
    j = (int)((const long long*)ei)[NE + e];
  } else {
    i = ei[e];
    j = ei[NE + e];
  }
  atomicOr(&bits[(size_t)i * NW + (j >> 5)], 1u << (j & 31));
}

// agg: block per node (128 thr = 2 waves, wave = head). Bitmap extraction
// (popcount + prefix + ffs), register softmax, BF16 gathers (8 rows/dwordx4).
__global__ __launch_bounds__(128) void agg_kernel(const unsigned short* __restrict__ xhb,
                                                  const float2* __restrict__ s1v,
                                                  const float2* __restrict__ s2v,
                                                  const unsigned* __restrict__ bits,
                                                  float* __restrict__ out) {
  const int i = blockIdx.x;
  const int t = threadIdx.x;
  const int h = t >> 6, lane = t & 63;
  __shared__ int   cjs[NH][256];
  __shared__ float wts[NH][256];

  const uint4 bv = *(const uint4*)(bits + (size_t)i * NW + lane * 4);
  const int myc = __popc(bv.x) + __popc(bv.y) + __popc(bv.z) + __popc(bv.w);
  int incl = myc;
#pragma unroll
  for (int s = 1; s < 64; s <<= 1) {
    const int v = __shfl_up(incl, s, 64);
    if (lane >= s) incl += v;
  }
  int pos = incl - myc;
  const int dt = __shfl(incl, 63, 64);
  const int d = __builtin_amdgcn_readfirstlane(dt > 256 ? 256 : dt);
  {
    unsigned wv; int bj;
    wv = bv.x; bj = lane * 128;
    while (wv) { const int bb = __ffs(wv) - 1; if (pos < 256) cjs[h][pos] = bj + bb; ++pos; wv &= wv - 1; }
    wv = bv.y; bj = lane * 128 + 32;
    while (wv) { const int bb = __ffs(wv) - 1; if (pos < 256) cjs[h][pos] = bj + bb; ++pos; wv &= wv - 1; }
    wv = bv.z; bj = lane * 128 + 64;
    while (wv) { const int bb = __ffs(wv) - 1; if (pos < 256) cjs[h][pos] = bj + bb; ++pos; wv &= wv - 1; }
    wv = bv.w; bj = lane * 128 + 96;
    while (wv) { const int bb = __ffs(wv) - 1; if (pos < 256) cjs[h][pos] = bj + bb; ++pos; wv &= wv - 1; }
  }
  __syncthreads();

  const unsigned short* base = xhb + (size_t)h * NN * OUTF;
  const int r8 = lane >> 3, c8 = lane & 7;
  float accv[8] = {0.f, 0.f, 0.f, 0.f, 0.f, 0.f, 0.f, 0.f};
  float inv;

  if (d == 0) {   // uniform softmax over ALL nodes (never hit at this density)
    for (int p = r8; p < NN; p += 8) {
      const short8 v = *(const short8*)(base + (size_t)p * OUTF + c8 * 8);
#pragma unroll
      for (int m = 0; m < 8; ++m) accv[m] += bf2f((unsigned short)v[m]);
    }
    inv = 1.f / (float)NN;
  } else if (d <= 64) {
    const bool kp = lane < d;
    const int j = kp ? cjs[h][lane] : 0;
    float sc = -1e30f;
    if (kp) {
      const float2 s1i2 = s1v[i];
      const float2 s2j2 = s2v[j];
      sc = (h ? s1i2.y : s1i2.x) + (h ? s2j2.y : s2j2.x);
      sc = (sc >= 0.f) ? sc : SLOPE * sc;
    }
    float m = sc;
#pragma unroll
    for (int s = 32; s > 0; s >>= 1) m = fmaxf(m, __shfl_xor(m, s, 64));
    const float wt = kp ? __expf(sc - m) : 0.f;
    float ds = wt;
#pragma unroll
    for (int s = 32; s > 0; s >>= 1) ds += __shfl_xor(ds, s, 64);
    inv = 1.f / ds;
#pragma unroll 2
    for (int p = 0; p < d; p += 8) {
      const int pr = p + r8;
      float ww = __shfl(wt, pr, 64);
      int   jj = __shfl(j,  pr, 64);
      ww = (pr < d) ? ww : 0.f;
      jj = (ww > 0.f) ? jj : 0;
      const short8 v = *(const short8*)(base + (size_t)jj * OUTF + c8 * 8);
#pragma unroll
      for (int m2 = 0; m2 < 8; ++m2) accv[m2] += ww * bf2f((unsigned short)v[m2]);
    }
  } else {
    // slow path: 64 < d <= 256 (list already unique)
    const float2 s1i2 = s1v[i];
    const float s1i = h ? s1i2.y : s1i2.x;
    float m = -1e30f;
    for (int p = lane; p < d; p += 64) {
      const float2 s2j2 = s2v[cjs[h][p]];
      float sc = s1i + (h ? s2j2.y : s2j2.x);
      sc = (sc >= 0.f) ? sc : SLOPE * sc;
      wts[h][p] = sc;
      m = fmaxf(m, sc);
    }
#pragma unroll
    for (int s = 32; s > 0; s >>= 1) m = fmaxf(m, __shfl_xor(m, s, 64));
    float ds = 0.f;
    for (int p = lane; p < d; p += 64) {
      const float w2 = __expf(wts[h][p] - m);
      wts[h][p] = w2;
      ds += w2;
    }
#pragma unroll
    for (int s = 32; s > 0; s >>= 1) ds += __shfl_xor(ds, s, 64);
    inv = 1.f / ds;
#pragma unroll 2
    for (int p = 0; p < d; p += 8) {
      const int pr = p + r8;
      const bool ok = pr < d;
      const float ww = ok ? wts[h][pr] : 0.f;
      const int   jj = ok ? cjs[h][pr] : 0;
      const short8 v = *(const short8*)(base + (size_t)jj * OUTF + c8 * 8);
#pragma unroll
      for (int m2 = 0; m2 < 8; ++m2) accv[m2] += ww * bf2f((unsigned short)v[m2]);
    }
  }

#pragma unroll
  for (int m2 = 0; m2 < 8; ++m2) {
    accv[m2] += __shfl_xor(accv[m2], 8, 64);
    accv[m2] += __shfl_xor(accv[m2], 16, 64);
    accv[m2] += __shfl_xor(accv[m2], 32, 64);
  }
  if (lane < 8) {
    float4 o0, o1;
    o0.x = accv[0] * inv; o0.y = accv[1] * inv;
    o0.z = accv[2] * inv; o0.w = accv[3] * inv;
    o1.x = accv[4] * inv; o1.y = accv[5] * inv;
    o1.z = accv[6] * inv; o1.w = accv[7] * inv;
    float* op = out + (size_t)i * (NH * OUTF) + h * OUTF + lane * 8;
    *(float4*)op = o0;
    *(float4*)(op + 4) = o1;
  }
}

extern "C" void kernel_launch(void* const* d_in, const int* in_sizes, int n_in,
                              void* d_out, int out_size, void* d_ws, size_t ws_size,
                              hipStream_t stream) {
  const float* x  = (const float*)d_in[0];
  const int*   ei = (const int*)d_in[1];
  const float* W  = (const float*)d_in[2];
  const float* a1 = (const float*)d_in[3];
  const float* a2 = (const float*)d_in[4];
  float* out = (float*)d_out;

  char* ws = (char*)d_ws;
  unsigned*       bits = (unsigned*)(ws);                            // 8 MB
  unsigned short* xhb  = (unsigned short*)(ws + (8u << 20));         // 2 MB
  float2*         s1v  = (float2*)(ws + (10u << 20));                // 64 KB
  float2*         s2v  = (float2*)(ws + (10u << 20) + (64u << 10));  // 64 KB

  gemm_kernel<<<512, 256, 0, stream>>>(x, W, a1, a2, xhb, s1v, s2v, bits);
  edge_kernel<<<NE / 256, 256, 0, stream>>>(ei, bits);
  agg_kernel<<<NN, 128, 0, stream>>>(xhb, s1v, s2v, bits, out);
}